// Round 1
// baseline (163.068 us; speedup 1.0000x reference)
//
#include <hip/hip_runtime.h>
#include <hip/hip_bf16.h>
#include <cstdint>

#define NB   32
#define CIN  128
#define HH   56
#define WWID 56
#define KOUT 256
#define HWS  (HH*WWID)          // 3136
#define NHW  (NB*HH*WWID)       // 100352
#define XCNT ((float)(NB*CIN*HH*WWID))   // 12845056
#define WCNT ((float)(KOUT*CIN*9))       // 294912

__global__ __launch_bounds__(64) void zero_sums_kernel(float* sums) {
    if (threadIdx.x < 2) sums[threadIdx.x] = 0.0f;
}

__device__ __forceinline__ void block_reduce_add(float v, float* dst) {
    // wave64 butterfly then cross-wave via LDS, one atomic per block
    #pragma unroll
    for (int off = 32; off > 0; off >>= 1) v += __shfl_down(v, off);
    __shared__ float ws4[4];
    int lane = threadIdx.x & 63, wid = threadIdx.x >> 6;
    if (lane == 0) ws4[wid] = v;
    __syncthreads();
    if (threadIdx.x == 0) {
        float s = ws4[0];
        int nw = (blockDim.x + 63) >> 6;
        for (int i = 1; i < nw; i++) s += ws4[i];
        atomicAdd(dst, s);
    }
}

// One thread per (n,h,w): read 128 channels (coalesced across lanes per c),
// pack sign bits into 4x u32, accumulate |x| partial sum.
__global__ __launch_bounds__(256) void pack_x_kernel(const float* __restrict__ x,
                                                     uint4* __restrict__ xpack,
                                                     float* __restrict__ sums) {
    int idx = blockIdx.x * 256 + threadIdx.x;      // exact grid: 392*256 == NHW
    int n  = idx / HWS;
    int hw = idx - n * HWS;
    const float* p = x + (size_t)n * CIN * HWS + hw;
    float asum = 0.0f;
    uint32_t b[4];
    #pragma unroll
    for (int j = 0; j < 4; j++) {
        uint32_t bits = 0;
        #pragma unroll
        for (int t = 0; t < 32; t++) {
            float v = p[(size_t)(j * 32 + t) * HWS];
            asum += fabsf(v);
            bits |= (v > 0.0f ? 1u : 0u) << t;
        }
        b[j] = bits;
    }
    xpack[idx] = make_uint4(b[0], b[1], b[2], b[3]);
    block_reduce_add(asum, &sums[0]);
}

// One thread per (k, tap): read 128 channels (stride 9), pack bits.
__global__ __launch_bounds__(256) void pack_w_kernel(const float* __restrict__ wgt,
                                                     uint4* __restrict__ wpack,
                                                     float* __restrict__ sums) {
    int idx = blockIdx.x * 256 + threadIdx.x;      // exact grid: 9*256 == 2304
    int k   = idx / 9;
    int tap = idx - k * 9;
    const float* p = wgt + (size_t)k * CIN * 9 + tap;
    float asum = 0.0f;
    uint32_t b[4];
    #pragma unroll
    for (int j = 0; j < 4; j++) {
        uint32_t bits = 0;
        #pragma unroll
        for (int t = 0; t < 32; t++) {
            float v = p[(size_t)(j * 32 + t) * 9];
            asum += fabsf(v);
            bits |= (v > 0.0f ? 1u : 0u) << t;
        }
        b[j] = bits;
    }
    wpack[idx] = make_uint4(b[0], b[1], b[2], b[3]);
    block_reduce_add(asum, &sums[1]);
}

// One block per (n,h) output row. wpack (256 k * 9 taps * 16B = 36 KB) in LDS.
// Wave g handles k in [g*64, g*64+64); lane = output w (lanes 56..63 idle).
// Per output: sum_signs = 128*nvalid - 2 * sum_taps popcount(x ^ w).
__global__ __launch_bounds__(256) void conv_kernel(const uint4* __restrict__ xpack,
                                                   const uint4* __restrict__ wpack,
                                                   const float* __restrict__ sums,
                                                   const float* __restrict__ bias,
                                                   float* __restrict__ out) {
    __shared__ uint4 wl[KOUT * 9];
    int tid = threadIdx.x;
    for (int i = tid; i < KOUT * 9; i += 256) wl[i] = wpack[i];

    int bid  = blockIdx.x;          // n*56 + h
    int n    = bid / HH;
    int h    = bid - n * HH;
    int wave = tid >> 6;
    int wcol = tid & 63;

    __syncthreads();

    if (wcol >= WWID) return;

    float scale = (sums[0] * (1.0f / XCNT)) * (sums[1] * (1.0f / WCNT));

    // Gather the 9-tap packed-x neighborhood into registers.
    uint64_t xa[9], xb[9];
    bool     vm[9];
    int      nvalid = 0;
    #pragma unroll
    for (int dy = 0; dy < 3; dy++) {
        int hy = h + dy - 1;
        #pragma unroll
        for (int dx = 0; dx < 3; dx++) {
            int wx = wcol + dx - 1;
            int t  = dy * 3 + dx;
            bool v = (hy >= 0) & (hy < HH) & (wx >= 0) & (wx < WWID);
            vm[t] = v;
            nvalid += v ? 1 : 0;
            uint4 q = v ? xpack[(n * HH + hy) * WWID + wx] : make_uint4(0, 0, 0, 0);
            xa[t] = ((uint64_t)q.y << 32) | q.x;
            xb[t] = ((uint64_t)q.w << 32) | q.z;
        }
    }
    int base = 128 * nvalid;

    int kend = wave * 64 + 64;
    for (int k = wave * 64; k < kend; k++) {
        const uint4* wp = &wl[k * 9];
        int diff = 0;
        #pragma unroll
        for (int t = 0; t < 9; t++) {
            if (vm[t]) {
                uint4 q = wp[t];
                uint64_t wa = ((uint64_t)q.y << 32) | q.x;
                uint64_t wb = ((uint64_t)q.w << 32) | q.z;
                diff += __popcll(xa[t] ^ wa) + __popcll(xb[t] ^ wb);
            }
        }
        float val = scale * (float)(base - 2 * diff) + bias[k];
        out[(((size_t)n * KOUT + k) * HH + h) * WWID + wcol] = val;
    }
}

extern "C" void kernel_launch(void* const* d_in, const int* in_sizes, int n_in,
                              void* d_out, int out_size, void* d_ws, size_t ws_size,
                              hipStream_t stream) {
    const float* x    = (const float*)d_in[0];
    const float* wgt  = (const float*)d_in[1];
    const float* bias = (const float*)d_in[2];
    float* out = (float*)d_out;

    // ws layout: [0..256) float sums[2]; xpack (NHW uint4); wpack (2304 uint4)
    float* sums  = (float*)d_ws;
    uint4* xpack = (uint4*)((char*)d_ws + 256);
    uint4* wpack = (uint4*)((char*)d_ws + 256 + (size_t)NHW * 16);

    hipLaunchKernelGGL(zero_sums_kernel, dim3(1), dim3(64), 0, stream, sums);
    hipLaunchKernelGGL(pack_x_kernel, dim3(NHW / 256), dim3(256), 0, stream, x, xpack, sums);
    hipLaunchKernelGGL(pack_w_kernel, dim3(9), dim3(256), 0, stream, wgt, wpack, sums);
    hipLaunchKernelGGL(conv_kernel, dim3(NB * HH), dim3(256), 0, stream, xpack, wpack, sums, bias, out);
}

// Round 2
// 134.365 us; speedup vs baseline: 1.2136x; 1.2136x over previous
//
#include <hip/hip_runtime.h>
#include <hip/hip_bf16.h>
#include <cstdint>

#define NB   32
#define CIN  128
#define HH   56
#define WW   56
#define KOUT 256
#define HWS  (HH*WW)            // 3136
#define NHW  (NB*HWS)           // 100352
#define XCNT ((float)(NB*CIN*HWS))
#define WCNT ((float)(KOUT*CIN*9))

__global__ __launch_bounds__(64) void zero_sums_kernel(float* sums) {
    if (threadIdx.x < 2) sums[threadIdx.x] = 0.0f;
}

__device__ __forceinline__ void block_reduce_add(float v, float* dst) {
    #pragma unroll
    for (int off = 32; off > 0; off >>= 1) v += __shfl_down(v, off);
    __shared__ float ws4[4];
    int lane = threadIdx.x & 63, wid = threadIdx.x >> 6;
    if (lane == 0) ws4[wid] = v;
    __syncthreads();
    if (threadIdx.x == 0) {
        float s = ws4[0];
        int nw = (blockDim.x + 63) >> 6;
        for (int i = 1; i < nw; i++) s += ws4[i];
        atomicAdd(dst, s);
    }
}

// One thread per (n,h,w): pack 128 channel signs into uint4, accumulate |x|.
__global__ __launch_bounds__(256) void pack_x_kernel(const float* __restrict__ x,
                                                     uint4* __restrict__ xpack,
                                                     float* __restrict__ sums) {
    int idx = blockIdx.x * 256 + threadIdx.x;      // grid: NHW/256
    int n  = idx / HWS;
    int hw = idx - n * HWS;
    const float* p = x + (size_t)n * CIN * HWS + hw;
    float asum = 0.0f;
    uint32_t b[4];
    #pragma unroll
    for (int j = 0; j < 4; j++) {
        uint32_t bits = 0;
        #pragma unroll
        for (int t = 0; t < 32; t++) {
            float v = p[(size_t)(j * 32 + t) * HWS];
            asum += fabsf(v);
            bits |= (v > 0.0f ? 1u : 0u) << t;
        }
        b[j] = bits;
    }
    xpack[idx] = make_uint4(b[0], b[1], b[2], b[3]);
    block_reduce_add(asum, &sums[0]);
}

// One thread per (k, tap): pack 128 channel signs; TRANSPOSED output [tap][k].
__global__ __launch_bounds__(256) void pack_w_kernel(const float* __restrict__ wgt,
                                                     uint4* __restrict__ wpackT,
                                                     float* __restrict__ sums) {
    int idx = blockIdx.x * 256 + threadIdx.x;      // grid: 9 (2304 threads)
    int k   = idx / 9;
    int tap = idx - k * 9;
    const float* p = wgt + (size_t)k * CIN * 9 + tap;
    float asum = 0.0f;
    uint32_t b[4];
    #pragma unroll
    for (int j = 0; j < 4; j++) {
        uint32_t bits = 0;
        #pragma unroll
        for (int t = 0; t < 32; t++) {
            float v = p[(size_t)(j * 32 + t) * 9];
            asum += fabsf(v);
            bits |= (v > 0.0f ? 1u : 0u) << t;
        }
        b[j] = bits;
    }
    wpackT[tap * KOUT + k] = make_uint4(b[0], b[1], b[2], b[3]);
    block_reduce_add(asum, &sums[1]);
}

// One block per (n,h). 256 threads, thread = k. Weights in 36 VGPRs/lane.
// x row-triple staged in LDS with zero halo; broadcast ds_read per w-iter.
// Edge taps removed algebraically: S = 1152 - 128*ninv - 2*raw + 2*sum_inv(pw),
// folded into per-thread FMA constants CB / F0 / F55 (interior loop edge-free).
// Outputs staged 8-wide in LDS, flushed as coalesced dwordx2.
__global__ __launch_bounds__(256) void conv_kernel(const uint4* __restrict__ xpack,
                                                   const uint4* __restrict__ wpackT,
                                                   const float* __restrict__ sums,
                                                   const float* __restrict__ bias,
                                                   float* __restrict__ out) {
    __shared__ uint4 xl[58 * 3];        // [col][row], col has +1 halo each side
    __shared__ float sbuf[KOUT * 10];   // [k][10] (8 used; stride 10 = align+banks)

    int tid = threadIdx.x;
    int bid = blockIdx.x;
    int n = bid / HH, h = bid - n * HH;
    int lane = tid & 63, wid = tid >> 6;

    // weights for k = tid (coalesced: [tap][k] layout)
    uint4 wq[9];
    #pragma unroll
    for (int t = 0; t < 9; t++) wq[t] = wpackT[t * KOUT + tid];

    // stage x cols (zero halo, zero invalid rows)
    for (int e = tid; e < 58 * 3; e += 256) {
        int col = e / 3, row = e - col * 3;
        int rw = col - 1, hy = h - 1 + row;
        uint4 q = make_uint4(0, 0, 0, 0);
        if (rw >= 0 && rw < WW && hy >= 0 && hy < HH)
            q = xpack[(n * HH + hy) * WW + rw];
        xl[e] = q;
    }

    float scale = (sums[0] * (1.0f / XCNT)) * (sums[1] * (1.0f / WCNT));
    float m2s   = -2.0f * scale;
    float cbase = 1152.0f * scale + bias[tid];

    // per-tap weight popcounts -> edge-correction constants (regs, die after this)
    int pw[9];
    #pragma unroll
    for (int t = 0; t < 9; t++)
        pw[t] = __popc(wq[t].x) + __popc(wq[t].y) + __popc(wq[t].z) + __popc(wq[t].w);
    int cs0 = pw[0] + pw[3] + pw[6];          // dx=0 column
    int cs2 = pw[2] + pw[5] + pw[8];          // dx=2 column
    int rterm = 0, cc0 = 0, cc2 = 0;
    if (h == 0)        { rterm = 2*(pw[0]+pw[1]+pw[2]) - 384; cc0 = 128 - 2*pw[0]; cc2 = 128 - 2*pw[2]; }
    else if (h == HH-1){ rterm = 2*(pw[6]+pw[7]+pw[8]) - 384; cc0 = 128 - 2*pw[6]; cc2 = 128 - 2*pw[8]; }
    float CB  = cbase + scale * (float)rterm;                      // interior w
    float F0  = CB + scale * (float)(2*cs0 - 384 + cc0);           // w = 0
    float F55 = CB + scale * (float)(2*cs2 - 384 + cc2);           // w = 55

    __syncthreads();

    float* sb = &sbuf[tid * 10];
    uint4 xs[3][3];   // [slot][row]; slot s always holds LDS col c with c%3==s

#define LOADCOL(S, C) { xs[S][0] = xl[(C)*3+0]; xs[S][1] = xl[(C)*3+1]; xs[S][2] = xl[(C)*3+2]; }
#define T4(a, q, wt) a += __popc((q).x^(wt).x) + __popc((q).y^(wt).y) + __popc((q).z^(wt).z) + __popc((q).w^(wt).w);
#define FLUSH(C) { \
    _Pragma("unroll") \
    for (int r = 0; r < 4; r++) { \
        int kl = r * 16 + (lane >> 2); \
        int wo = (lane & 3) * 2; \
        float2 v2 = *(float2*)&sbuf[(wid * 64 + kl) * 10 + wo]; \
        *(float2*)&out[(size_t)(n * KOUT + wid * 64 + kl) * HWS + h * WW + (C) * 8 + wo] = v2; \
    } }
#define BODY(L, M, R, W) { \
    LOADCOL(R, (W) + 2) \
    int a0 = 0, a1 = 0, a2 = 0; \
    T4(a0, xs[L][0], wq[0]) T4(a0, xs[M][0], wq[1]) T4(a0, xs[R][0], wq[2]) \
    T4(a1, xs[L][1], wq[3]) T4(a1, xs[M][1], wq[4]) T4(a1, xs[R][1], wq[5]) \
    T4(a2, xs[L][2], wq[6]) T4(a2, xs[M][2], wq[7]) T4(a2, xs[R][2], wq[8]) \
    sb[(W) & 7] = fmaf(m2s, (float)(a0 + a1 + a2), CB); \
    if (((W) & 7) == 7) FLUSH((W) >> 3) \
}

    // preload LDS cols 1,2 into slots 1,2
    LOADCOL(1, 1)
    LOADCOL(2, 2)

    // w = 0: dx=0 is pad (contributes cs0); slot1 = real col 0, slot2 = real col 1
    {
        int a0 = cs0, a1 = 0, a2 = 0;
        T4(a0, xs[1][0], wq[1]) T4(a0, xs[2][0], wq[2])
        T4(a1, xs[1][1], wq[4]) T4(a1, xs[2][1], wq[5])
        T4(a2, xs[1][2], wq[7]) T4(a2, xs[2][2], wq[8])
        sb[0] = fmaf(m2s, (float)(a0 + a1 + a2), F0);
    }

    // interior w = 1..54, 18 unrolled trios; phases (L,M,R) = (1,2,0),(2,0,1),(0,1,2)
    #pragma unroll 1
    for (int w = 1; w <= 52; w += 3) {
        BODY(1, 2, 0, w)
        BODY(2, 0, 1, w + 1)
        BODY(0, 1, 2, w + 2)
    }

    // w = 55: dx=2 is pad (cs2); slot1 = real col 54, slot2 = real col 55
    {
        int a0 = cs2, a1 = 0, a2 = 0;
        T4(a0, xs[1][0], wq[0]) T4(a0, xs[2][0], wq[1])
        T4(a1, xs[1][1], wq[3]) T4(a1, xs[2][1], wq[4])
        T4(a2, xs[1][2], wq[6]) T4(a2, xs[2][2], wq[7])
        sb[7] = fmaf(m2s, (float)(a0 + a1 + a2), F55);
        FLUSH(6)
    }
}

extern "C" void kernel_launch(void* const* d_in, const int* in_sizes, int n_in,
                              void* d_out, int out_size, void* d_ws, size_t ws_size,
                              hipStream_t stream) {
    const float* x    = (const float*)d_in[0];
    const float* wgt  = (const float*)d_in[1];
    const float* bias = (const float*)d_in[2];
    float* out = (float*)d_out;

    float* sums   = (float*)d_ws;
    uint4* xpack  = (uint4*)((char*)d_ws + 256);
    uint4* wpackT = (uint4*)((char*)d_ws + 256 + (size_t)NHW * 16);

    hipLaunchKernelGGL(zero_sums_kernel, dim3(1), dim3(64), 0, stream, sums);
    hipLaunchKernelGGL(pack_x_kernel, dim3(NHW / 256), dim3(256), 0, stream, x, xpack, sums);
    hipLaunchKernelGGL(pack_w_kernel, dim3(9), dim3(256), 0, stream, wgt, wpackT, sums);
    hipLaunchKernelGGL(conv_kernel, dim3(NB * HH), dim3(256), 0, stream, xpack, wpackT, sums, bias, out);
}

// Round 4
// 109.955 us; speedup vs baseline: 1.4830x; 1.2220x over previous
//
#include <hip/hip_runtime.h>
#include <hip/hip_bf16.h>
#include <cstdint>

#define NB   32
#define CIN  128
#define HH   56
#define WW   56
#define KOUT 256
#define HWS  (HH*WW)            // 3136
#define NHW  (NB*HWS)           // 100352
#define XCNT ((float)(NB*CIN*HWS))
#define WCNT ((float)(KOUT*CIN*9))

__global__ __launch_bounds__(64) void zero_sums_kernel(float* sums) {
    if (threadIdx.x < 2) sums[threadIdx.x] = 0.0f;
}

__device__ __forceinline__ void block_reduce_add(float v, float* dst) {
    #pragma unroll
    for (int off = 32; off > 0; off >>= 1) v += __shfl_down(v, off);
    __shared__ float ws4[4];
    int lane = threadIdx.x & 63, wid = threadIdx.x >> 6;
    if (lane == 0) ws4[wid] = v;
    __syncthreads();
    if (threadIdx.x == 0) {
        float s = ws4[0];
        int nw = (blockDim.x + 63) >> 6;
        for (int i = 1; i < nw; i++) s += ws4[i];
        atomicAdd(dst, s);
    }
}

// Thread per (spatial idx, 32-channel word j). Grid 1568 blocks (6/CU).
__global__ __launch_bounds__(256) void pack_x_kernel(const float* __restrict__ x,
                                                     uint32_t* __restrict__ xpackw,
                                                     float* __restrict__ sums) {
    int j   = blockIdx.x / (NHW / 256);            // 0..3, uniform per block
    int idx = (blockIdx.x - j * (NHW / 256)) * 256 + threadIdx.x;
    int n  = idx / HWS;
    int hw = idx - n * HWS;
    const float* p = x + (size_t)n * CIN * HWS + (size_t)(j * 32) * HWS + hw;
    float asum = 0.0f;
    uint32_t bits = 0;
    #pragma unroll
    for (int t = 0; t < 32; t++) {
        float v = p[(size_t)t * HWS];
        asum += fabsf(v);
        bits |= (v > 0.0f ? 1u : 0u) << t;
    }
    xpackw[idx * 4 + j] = bits;
    block_reduce_add(asum, &sums[0]);
}

// Thread per (k, tap, word j): block = (tap, j) [36 blocks], lane = k (256).
__global__ __launch_bounds__(256) void pack_w_kernel(const float* __restrict__ wgt,
                                                     uint32_t* __restrict__ wpackTw,
                                                     float* __restrict__ sums) {
    int k   = threadIdx.x;
    int tap = blockIdx.x >> 2;
    int j   = blockIdx.x & 3;
    const float* p = wgt + (size_t)k * CIN * 9 + (size_t)(j * 32) * 9 + tap;
    float asum = 0.0f;
    uint32_t bits = 0;
    #pragma unroll
    for (int t = 0; t < 32; t++) {
        float v = p[(size_t)t * 9];
        asum += fabsf(v);
        bits |= (v > 0.0f ? 1u : 0u) << t;
    }
    wpackTw[(tap * KOUT + k) * 4 + j] = bits;
    block_reduce_add(asum, &sums[1]);
}

// One block per (n,h). Thread = k. Weights in 36 VGPRs/lane.
// 6-slot column rotation (slot = col % 6), prefetch distance 4 BODYs.
// Col 6 is loaded explicitly in the w=0 edge block (slot 0 idle there) —
// the prologue covers cols 0..5 and BODY prefetches start at col 7.
__global__ __launch_bounds__(256) void conv_kernel(const uint4* __restrict__ xpack,
                                                   const uint4* __restrict__ wpackT,
                                                   const float* __restrict__ sums,
                                                   const float* __restrict__ bias,
                                                   float* __restrict__ out) {
    __shared__ uint4 xl[58 * 3];        // [col][row], col 0 and 57 are halo
    __shared__ float sbuf[KOUT * 10];   // [k][10] (8 used; stride 10 vs banks)

    int tid = threadIdx.x;
    int bid = blockIdx.x;
    int n = bid / HH, h = bid - n * HH;
    int lane = tid & 63, wid = tid >> 6;

    uint4 wq[9];
    #pragma unroll
    for (int t = 0; t < 9; t++) wq[t] = wpackT[t * KOUT + tid];

    for (int e = tid; e < 58 * 3; e += 256) {
        int col = e / 3, row = e - col * 3;
        int rw = col - 1, hy = h - 1 + row;
        uint4 q = make_uint4(0, 0, 0, 0);
        if (rw >= 0 && rw < WW && hy >= 0 && hy < HH)
            q = xpack[(n * HH + hy) * WW + rw];
        xl[e] = q;
    }

    float scale = (sums[0] * (1.0f / XCNT)) * (sums[1] * (1.0f / WCNT));
    float m2s   = -2.0f * scale;
    float cbase = 1152.0f * scale + bias[tid];

    int pw[9];
    #pragma unroll
    for (int t = 0; t < 9; t++)
        pw[t] = __popc(wq[t].x) + __popc(wq[t].y) + __popc(wq[t].z) + __popc(wq[t].w);
    int cs0 = pw[0] + pw[3] + pw[6];
    int cs2 = pw[2] + pw[5] + pw[8];
    int rterm = 0, cc0 = 0, cc2 = 0;
    if (h == 0)        { rterm = 2*(pw[0]+pw[1]+pw[2]) - 384; cc0 = 128 - 2*pw[0]; cc2 = 128 - 2*pw[2]; }
    else if (h == HH-1){ rterm = 2*(pw[6]+pw[7]+pw[8]) - 384; cc0 = 128 - 2*pw[6]; cc2 = 128 - 2*pw[8]; }
    float CB  = cbase + scale * (float)rterm;
    float F0  = CB + scale * (float)(2*cs0 - 384 + cc0);
    float F55 = CB + scale * (float)(2*cs2 - 384 + cc2);

    __syncthreads();

    float* sb = &sbuf[tid * 10];
    uint4 xs[6][3];   // slot s holds LDS col c with c % 6 == s

#define LOADCOL(S, C) { xs[S][0] = xl[(C)*3+0]; xs[S][1] = xl[(C)*3+1]; xs[S][2] = xl[(C)*3+2]; }
#define MINC(c) ((c) > 57 ? 57 : (c))
#define T4(a, q, wt) a += __popc((q).x^(wt).x) + __popc((q).y^(wt).y) + __popc((q).z^(wt).z) + __popc((q).w^(wt).w);
#define FLUSH(C) { \
    _Pragma("unroll") \
    for (int r = 0; r < 4; r++) { \
        int kl = r * 16 + (lane >> 2); \
        int wo = (lane & 3) * 2; \
        float2 v2 = *(float2*)&sbuf[(wid * 64 + kl) * 10 + wo]; \
        *(float2*)&out[(size_t)(n * KOUT + wid * 64 + kl) * HWS + h * WW + (C) * 8 + wo] = v2; \
    } }
// Consume cols W..W+2 (slots L,M,R); prefetch col PC into slot L (after its reads).
#define BODY(L, M, R, W, PC) { \
    int a0 = 0, a1 = 0, a2 = 0; \
    T4(a0, xs[L][0], wq[0]) T4(a0, xs[M][0], wq[1]) T4(a0, xs[R][0], wq[2]) \
    T4(a1, xs[L][1], wq[3]) T4(a1, xs[M][1], wq[4]) T4(a1, xs[R][1], wq[5]) \
    T4(a2, xs[L][2], wq[6]) T4(a2, xs[M][2], wq[7]) T4(a2, xs[R][2], wq[8]) \
    LOADCOL(L, PC) \
    sb[(W) & 7] = fmaf(m2s, (float)(a0 + a1 + a2), CB); \
    if (((W) & 7) == 7) FLUSH((W) >> 3) \
}

    // prologue: slots 0..5 = cols 0..5
    LOADCOL(0, 0) LOADCOL(1, 1) LOADCOL(2, 2)
    LOADCOL(3, 3) LOADCOL(4, 4) LOADCOL(5, 5)

    // w = 0: dx=0 pad (contributes cs0); M = col 1 (slot 1), R = col 2 (slot 2).
    // Also load col 6 into slot 0 (first consumer: BODY(4) as R — distance 4).
    {
        int a0 = cs0, a1 = 0, a2 = 0;
        T4(a0, xs[1][0], wq[1]) T4(a0, xs[2][0], wq[2])
        T4(a1, xs[1][1], wq[4]) T4(a1, xs[2][1], wq[5])
        T4(a2, xs[1][2], wq[7]) T4(a2, xs[2][2], wq[8])
        LOADCOL(0, 6)
        sb[0] = fmaf(m2s, (float)(a0 + a1 + a2), F0);
    }

    // interior w = 1..54: 9 trips x 6 phases
    #pragma unroll 1
    for (int w = 1; w <= 49; w += 6) {
        BODY(1, 2, 3, w,     MINC(w + 6))
        BODY(2, 3, 4, w + 1, MINC(w + 7))
        BODY(3, 4, 5, w + 2, MINC(w + 8))
        BODY(4, 5, 0, w + 3, MINC(w + 9))
        BODY(5, 0, 1, w + 4, MINC(w + 10))
        BODY(0, 1, 2, w + 5, MINC(w + 11))
    }

    // w = 55: dx=2 pad (cs2); L = col 55 (slot 1), M = col 56 (slot 2)
    {
        int a0 = cs2, a1 = 0, a2 = 0;
        T4(a0, xs[1][0], wq[0]) T4(a0, xs[2][0], wq[1])
        T4(a1, xs[1][1], wq[3]) T4(a1, xs[2][1], wq[4])
        T4(a2, xs[1][2], wq[6]) T4(a2, xs[2][2], wq[7])
        sb[7] = fmaf(m2s, (float)(a0 + a1 + a2), F55);
        FLUSH(6)
    }
}

extern "C" void kernel_launch(void* const* d_in, const int* in_sizes, int n_in,
                              void* d_out, int out_size, void* d_ws, size_t ws_size,
                              hipStream_t stream) {
    const float* x    = (const float*)d_in[0];
    const float* wgt  = (const float*)d_in[1];
    const float* bias = (const float*)d_in[2];
    float* out = (float*)d_out;

    float* sums   = (float*)d_ws;
    uint4* xpack  = (uint4*)((char*)d_ws + 256);
    uint4* wpackT = (uint4*)((char*)d_ws + 256 + (size_t)NHW * 16);

    hipLaunchKernelGGL(zero_sums_kernel, dim3(1), dim3(64), 0, stream, sums);
    hipLaunchKernelGGL(pack_w_kernel, dim3(36), dim3(256), 0, stream, wgt, (uint32_t*)wpackT, sums);
    hipLaunchKernelGGL(pack_x_kernel, dim3(4 * NHW / 256), dim3(256), 0, stream, x, (uint32_t*)xpack, sums);
    hipLaunchKernelGGL(conv_kernel, dim3(NB * HH), dim3(256), 0, stream, xpack, wpackT, sums, bias, out);
}